// Round 2
// baseline (137.005 us; speedup 1.0000x reference)
//
#include <hip/hip_runtime.h>

#define BB 4
#define NN 2048
#define FF 128
#define NP 2176  // padded WhT row stride (shorts)
#define ALPHA 0.2f
#define SHIFT_C 16.0f  // exp(x-16): x=LR(f1+f2) bounded ~|10|; masked -> p=0 via bit-multiply

typedef short bf16x8 __attribute__((ext_vector_type(8)));
typedef float f32x4 __attribute__((ext_vector_type(4)));
typedef unsigned u32;

__device__ inline short f2bf(float f) {  // RNE float -> bf16 bits
    union { float f; unsigned u; } v; v.f = f;
    unsigned r = (v.u + 0x7FFFu + ((v.u >> 16) & 1u)) >> 16;
    return (short)r;
}
__device__ inline float bf2f(short s) {
    union { float f; unsigned u; } v;
    v.u = ((unsigned)(unsigned short)s) << 16;
    return v.f;
}

// async 16B global->LDS (gfx950); HW writes lds_base + lane*16
__device__ inline void cp16(const void* g, void* l) {
    __builtin_amdgcn_global_load_lds(
        (const __attribute__((address_space(1))) u32*)g,
        (__attribute__((address_space(3))) u32*)l, 16, 0, 0);
}

// ---------------------------------------------------------------------------
// k_wh: unchanged (passed).
// ---------------------------------------------------------------------------
__global__ __launch_bounds__(256) void k_wh(const float* __restrict__ h,
                                            const float* __restrict__ W,
                                            const float* __restrict__ a,
                                            const int* __restrict__ adj,
                                            short* __restrict__ WhHiT,
                                            short* __restrict__ WhLoT,
                                            float* __restrict__ f1,
                                            float* __restrict__ f2,
                                            u32* __restrict__ adjp) {
    __shared__ float Wa[2 * FF];
    __shared__ float hs[16 * 128];  // 8 KB
    int tid = threadIdx.x;
    int r0 = blockIdx.x * 16;

    {
        int fin = tid & 127;
        const float* av = (tid < 128) ? a : (a + FF);
        const float* wr = W + (size_t)fin * FF;
        float s = 0.f;
        for (int o = 0; o < FF; o += 4) {
            float4 wv = *(const float4*)(wr + o);
            float4 avv = *(const float4*)(av + o);
            s += wv.x * avv.x + wv.y * avv.y + wv.z * avv.z + wv.w * avv.w;
        }
        Wa[(tid < 128 ? 0 : FF) + fin] = s;
    }
    {
        const float4* src = (const float4*)(h + (size_t)r0 * FF);
        float4* dst = (float4*)hs;
        dst[tid] = src[tid];
        dst[256 + tid] = src[256 + tid];
    }
    // de-serialized adj pack: 512 blocks * 256 thr = 131072 = 2048 rows * 64 words
    {
        int g = blockIdx.x * 256 + tid;
        int row = g >> 6, wd = g & 63;
        const int4* ar = (const int4*)(adj + (size_t)row * NN + wd * 32);
        u32 word = 0;
#pragma unroll
        for (int q = 0; q < 8; ++q) {
            int4 v = ar[q];
            word |= (u32)(v.x > 0) << (q * 4);
            word |= (u32)(v.y > 0) << (q * 4 + 1);
            word |= (u32)(v.z > 0) << (q * 4 + 2);
            word |= (u32)(v.w > 0) << (q * 4 + 3);
        }
        adjp[row * 64 + wd] = word;
    }
    __syncthreads();

    {
        int w = tid >> 6, lane = tid & 63;
        float wa1_0 = Wa[lane], wa1_1 = Wa[lane + 64];
        float wa2_0 = Wa[FF + lane], wa2_1 = Wa[FF + lane + 64];
        for (int rr = 0; rr < 4; ++rr) {
            int rloc = w * 4 + rr;
            int row = r0 + rloc;
            float x0 = hs[rloc * FF + lane], x1 = hs[rloc * FF + lane + 64];
            float s1 = x0 * wa1_0 + x1 * wa1_1;
            float s2 = x0 * wa2_0 + x1 * wa2_1;
#pragma unroll
            for (int m = 32; m >= 1; m >>= 1) {
                s1 += __shfl_xor(s1, m, 64);
                s2 += __shfl_xor(s2, m, 64);
            }
            if (lane == 0) { f1[row] = s1; f2[row] = s2; }
        }
    }

    int f4 = (tid & 31) * 4;
    int rg = tid >> 5;  // 0..7
    float acc[2][4];
#pragma unroll
    for (int rr = 0; rr < 2; ++rr)
#pragma unroll
        for (int cc = 0; cc < 4; ++cc) acc[rr][cc] = 0.f;

    for (int k0 = 0; k0 < FF; k0 += 4) {
        float4 wv[4];
#pragma unroll
        for (int kk = 0; kk < 4; ++kk)
            wv[kk] = *(const float4*)(W + (size_t)(k0 + kk) * FF + f4);
        float4 hv[2];
#pragma unroll
        for (int rr = 0; rr < 2; ++rr)
            hv[rr] = *(const float4*)(hs + (rg * 2 + rr) * FF + k0);
#pragma unroll
        for (int rr = 0; rr < 2; ++rr) {
            float hk[4] = {hv[rr].x, hv[rr].y, hv[rr].z, hv[rr].w};
#pragma unroll
            for (int kk = 0; kk < 4; ++kk) {
                acc[rr][0] += hk[kk] * wv[kk].x;
                acc[rr][1] += hk[kk] * wv[kk].y;
                acc[rr][2] += hk[kk] * wv[kk].z;
                acc[rr][3] += hk[kk] * wv[kk].w;
            }
        }
    }
    int rloc = r0 + rg * 2;
    int b = rloc >> 11;
    int j = rloc & (NN - 1);  // even
#pragma unroll
    for (int cc = 0; cc < 4; ++cc) {
        float v0 = acc[0][cc], v1 = acc[1][cc];
        short h0 = f2bf(v0), h1 = f2bf(v1);
        short l0 = f2bf(v0 - bf2f(h0)), l1 = f2bf(v1 - bf2f(h1));
        size_t off = (size_t)(b * FF + f4 + cc) * NP + j;
        *(short2*)(WhHiT + off) = make_short2(h0, h1);
        *(short2*)(WhLoT + off) = make_short2(l0, l1);
    }
}

// ---------------------------------------------------------------------------
// k_attn flash-v7: depth-2 B staging (3 period-buffers) + counted waits.
// cp16 for period p+2 is issued in period p (sched_barrier pins cp16 issue
// before the register prefetch loads, so the compiler's implicit vmcnt wait
// on the prefetched regs in period p+1 retires them with ~2 periods slack).
// Barrier is raw s_barrier with lgkmcnt(0) ONLY -- no vmcnt drain in the
// main loop (the round-1 null falsified LDS-pipe-bound; this targets the
// __syncthreads vmcnt(0) drain).  Partial-acc merge lives in buf1 (never a
// wrap-staging target, so in-flight wrapped cp16s can't corrupt it).
// LDS: B 3x16384 + A 2x5120 + row_ps/row_inv = 60544 B (2 blocks/CU).
// ---------------------------------------------------------------------------
__global__ __launch_bounds__(512, 4) void k_attn(const short* __restrict__ WhHiT,
                                                 const short* __restrict__ WhLoT,
                                                 const u32* __restrict__ adjp,
                                                 const float* __restrict__ f1,
                                                 const float* __restrict__ f2,
                                                 float* __restrict__ out) {
    __shared__ __align__(16) char lds[60544];
    char* Bb = lds;                           // 3 x 16384 (per period-buf: 2 steps x (hi 4K + lo 4K))
    char* Ab = lds + 49152;                   // 2 x 5120
    float* row_ps = (float*)(lds + 59392);    // [8][32]
    float* row_inv = (float*)(lds + 60416);   // [32]
    float* pP = (float*)(lds + 16384);        // partial-acc merge (8 KB), reuses buf1 post-loop

    int tid = threadIdx.x;
    int w = tid >> 6, lane = tid & 63;        // w 0..7
    int blk = blockIdx.x;
    int b = blk >> 7;
    int tile = (blk >> 1) & 63;
    int half = blk & 1;
    int i0 = tile * 32;

    int r_a = lane & 15, kg = lane >> 4;
    int st = w >> 2, ni = w & 3;              // compute role: step-parity x fo-block
    int csw = kg ^ ((r_a >> 1) & 3);          // swizzled B chunk (read side)

    // A-build role: thread -> (row rb, j-pair jp); all 512 threads
    int rb = tid & 31;
    int jp = (tid >> 5) & 15;
    float f1i = f1[b * NN + i0 + rb];
    const u32* aprow = adjp + (size_t)(i0 + rb) * 64;
    const float* f2b = f2 + b * NN;
    int aoff = (rb >> 4) * 1280 + (rb & 15) * 80 + jp * 4;

    // B-stage role: waves 0-3 hi, 4-7 lo; 16 fo each within block's half.
    // Source column chunk pre-swizzled (inverse of read swizzle).
    int isLo = w >> 2;
    int sub = w & 3;
    int fo_s = half * 64 + sub * 16 + (lane >> 2);
    int oc_s = (lane & 3) ^ ((lane >> 3) & 3);
    const short* gB = (isLo ? WhLoT : WhHiT) + (size_t)(b * FF + fo_s) * NP + oc_s * 8;
    int bB = isLo * 4096 + sub * 1024;  // wave-uniform base within one 8KB step-buf

    f32x4 acc0 = {0.f, 0.f, 0.f, 0.f};   // mi=0 tile partial
    f32x4 acc1 = {0.f, 0.f, 0.f, 0.f};   // mi=1 tile partial
    float sp = 0.f;

    // ---- prologue: stage periods 0 AND 1; build A0; prefetch regs for A1 ----
    cp16(gB, Bb + bB);                     // period 0, step 0
    cp16(gB + 32, Bb + 8192 + bB);         // period 0, step 1
    cp16(gB + 64, Bb + 16384 + bB);        // period 1, step 2
    cp16(gB + 96, Bb + 16384 + 8192 + bB); // period 1, step 3
    __builtin_amdgcn_sched_barrier(0);
    {
        float2 qa = *(const float2*)(f2b + jp * 2);
        float2 qb = *(const float2*)(f2b + 32 + jp * 2);
        u32 wa = aprow[0], wb = aprow[1];
        float x;
        x = f1i + qa.x; x = fmaxf(x, ALPHA * x);
        float p00 = __expf(x - SHIFT_C) * (float)((wa >> (jp * 2)) & 1u);
        x = f1i + qa.y; x = fmaxf(x, ALPHA * x);
        float p01 = __expf(x - SHIFT_C) * (float)((wa >> (jp * 2 + 1)) & 1u);
        x = f1i + qb.x; x = fmaxf(x, ALPHA * x);
        float p10 = __expf(x - SHIFT_C) * (float)((wb >> (jp * 2)) & 1u);
        x = f1i + qb.y; x = fmaxf(x, ALPHA * x);
        float p11 = __expf(x - SHIFT_C) * (float)((wb >> (jp * 2 + 1)) & 1u);
        sp += p00 + p01 + p10 + p11;
        union { float f; u32 u; } u0, u1;
        u0.f = p00; u1.f = p01;
        *(u32*)(Ab + aoff) = ((u0.u + 0x8000u) >> 16) | (((u1.u + 0x8000u) >> 16) << 16);
        u0.f = p10; u1.f = p11;
        *(u32*)(Ab + 2560 + aoff) = ((u0.u + 0x8000u) >> 16) | (((u1.u + 0x8000u) >> 16) << 16);
    }
    float2 pfa = *(const float2*)(f2b + 64 + jp * 2);
    float2 pfb = *(const float2*)(f2b + 96 + jp * 2);
    u32 pwa = aprow[2], pwb = aprow[3];
    asm volatile("s_waitcnt vmcnt(0) lgkmcnt(0)" ::: "memory");
    __builtin_amdgcn_s_barrier();
    __builtin_amdgcn_sched_barrier(0);

    int cur = 0;  // buffer holding period p's B tiles; stage target = (cur+2)%3
    for (int p = 0; p < 32; ++p) {
        int par = p & 1, opar = par ^ 1;
        int stg = (cur == 0) ? 2 : cur - 1;  // (cur+2) mod 3
        // stage B for period p+2 (wrapped at p>=30; wrap lands in buf2/buf0 only)
        {
            int j0n = ((2 * p + 4) & 63) * 32;
            int j1n = ((2 * p + 5) & 63) * 32;
            cp16(gB + j0n, Bb + stg * 16384 + bB);
            cp16(gB + j1n, Bb + stg * 16384 + 8192 + bB);
        }
        __builtin_amdgcn_sched_barrier(0);  // pin cp16 issue before prefetch loads
        // build A for period p+1 from prefetched regs (implicit vmcnt wait here
        // retires cp16s issued last period -> B for p+1 landed, 2-period slack)
        {
            float x;
            x = f1i + pfa.x; x = fmaxf(x, ALPHA * x);
            float p00 = __expf(x - SHIFT_C) * (float)((pwa >> (jp * 2)) & 1u);
            x = f1i + pfa.y; x = fmaxf(x, ALPHA * x);
            float p01 = __expf(x - SHIFT_C) * (float)((pwa >> (jp * 2 + 1)) & 1u);
            x = f1i + pfb.x; x = fmaxf(x, ALPHA * x);
            float p10 = __expf(x - SHIFT_C) * (float)((pwb >> (jp * 2)) & 1u);
            x = f1i + pfb.y; x = fmaxf(x, ALPHA * x);
            float p11 = __expf(x - SHIFT_C) * (float)((pwb >> (jp * 2 + 1)) & 1u);
            if (p < 31) sp += p00 + p01 + p10 + p11;  // exclude wrapped rebuild
            union { float f; u32 u; } u0, u1;
            u0.f = p00; u1.f = p01;
            *(u32*)(Ab + opar * 5120 + aoff) =
                ((u0.u + 0x8000u) >> 16) | (((u1.u + 0x8000u) >> 16) << 16);
            u0.f = p10; u1.f = p11;
            *(u32*)(Ab + opar * 5120 + 2560 + aoff) =
                ((u0.u + 0x8000u) >> 16) | (((u1.u + 0x8000u) >> 16) << 16);
        }
        // prefetch regs for period p+2's A-build (wrapped)
        {
            int s0 = (2 * p + 4) & 63, s1 = (2 * p + 5) & 63;
            pfa = *(const float2*)(f2b + s0 * 32 + jp * 2);
            pfb = *(const float2*)(f2b + s1 * 32 + jp * 2);
            pwa = aprow[s0]; pwb = aprow[s1];
        }
        // compute: wave (st,ni) does step 2p+st, BOTH mi tiles.
        {
            char* bbase = Bb + cur * 16384 + st * 8192;
            char* abase = Ab + par * 5120 + st * 2560;
            int boff = (ni * 16 + r_a) * 64 + csw * 16;
            int aoffr = r_a * 80 + kg * 16;
            bf16x8 a0 = *(const bf16x8*)(abase + aoffr);
            bf16x8 a1 = *(const bf16x8*)(abase + 1280 + aoffr);
            bf16x8 bh = *(const bf16x8*)(bbase + boff);
            bf16x8 bl = *(const bf16x8*)(bbase + 4096 + boff);
            acc0 = __builtin_amdgcn_mfma_f32_16x16x32_bf16(a0, bh, acc0, 0, 0, 0);
            acc1 = __builtin_amdgcn_mfma_f32_16x16x32_bf16(a1, bh, acc1, 0, 0, 0);
            acc0 = __builtin_amdgcn_mfma_f32_16x16x32_bf16(a0, bl, acc0, 0, 0, 0);
            acc1 = __builtin_amdgcn_mfma_f32_16x16x32_bf16(a1, bl, acc1, 0, 0, 0);
        }
        // counted barrier: LDS ops must be done (A writes visible, B reads
        // retired for WAR), but B-staging loads stay IN FLIGHT across it.
        asm volatile("s_waitcnt lgkmcnt(0)" ::: "memory");
        __builtin_amdgcn_s_barrier();
        __builtin_amdgcn_sched_barrier(0);
        cur = (cur == 2) ? 0 : cur + 1;
    }

    // ---- row sums + st-partial exchange (pP = buf1: never wrap-staged) ----
    sp += __shfl_xor(sp, 32, 64);              // jp 2w <-> 2w+1, same row rb
    if (lane < 32) row_ps[w * 32 + lane] = sp;
    if (st == 0) {
        *(f32x4*)(pP + (ni * 2 + 0) * 256 + lane * 4) = acc0;
        *(f32x4*)(pP + (ni * 2 + 1) * 256 + lane * 4) = acc1;
    }
    __syncthreads();
    if (tid < 32) {
        float t = 0.f;
#pragma unroll
        for (int ww = 0; ww < 8; ++ww) t += row_ps[ww * 32 + tid];
        row_inv[tid] = 1.0f / t;
    }
    __syncthreads();

    // ---- st=1 waves merge partials and store both mi tiles, normalized ----
    if (st == 1) {
        acc0 += *(const f32x4*)(pP + (ni * 2 + 0) * 256 + lane * 4);
        acc1 += *(const f32x4*)(pP + (ni * 2 + 1) * 256 + lane * 4);
        float* ob = out + ((size_t)b * NN + i0) * FF + half * 64 + ni * 16;
#pragma unroll
        for (int q = 0; q < 4; ++q) {
            int rr0 = kg * 4 + q;
            ob[(size_t)rr0 * FF + r_a] = acc0[q] * row_inv[rr0];
            int rr1 = 16 + kg * 4 + q;
            ob[(size_t)rr1 * FF + r_a] = acc1[q] * row_inv[rr1];
        }
    }
}

// ---------------------------------------------------------------------------
extern "C" void kernel_launch(void* const* d_in, const int* in_sizes, int n_in,
                              void* d_out, int out_size, void* d_ws, size_t ws_size,
                              hipStream_t stream) {
    const float* h   = (const float*)d_in[0];
    const int*   adj = (const int*)d_in[1];
    const float* W   = (const float*)d_in[2];
    const float* a   = (const float*)d_in[3];
    float* out = (float*)d_out;

    short* WhHiT = (short*)d_ws;                          // 2.13 MB
    short* WhLoT = WhHiT + (size_t)BB * FF * NP;          // 2.13 MB
    float* f1 = (float*)(WhLoT + (size_t)BB * FF * NP);   // 32 KB
    float* f2 = f1 + (size_t)BB * NN;                     // 32 KB
    u32* adjp = (u32*)(f2 + (size_t)BB * NN);             // 512 KB (total ~4.83 MB, proven)

    k_wh<<<(BB * NN) / 16, 256, 0, stream>>>(h, W, a, adj, WhHiT, WhLoT, f1, f2, adjp);
    k_attn<<<512, 512, 0, stream>>>(WhHiT, WhLoT, adjp, f1, f2, out);
}

// Round 3
// 129.195 us; speedup vs baseline: 1.0604x; 1.0604x over previous
//
#include <hip/hip_runtime.h>

#define BB 4
#define NN 2048
#define FF 128
#define NP 2176  // padded WhT row stride (shorts)
#define ALPHA 0.2f
#define SHIFT_C 16.0f  // exp(x-16): x=LR(f1+f2) bounded ~|10|; masked -> p=0 via bit-multiply

typedef short bf16x8 __attribute__((ext_vector_type(8)));
typedef float f32x4 __attribute__((ext_vector_type(4)));
typedef unsigned u32;

__device__ inline short f2bf(float f) {  // RNE float -> bf16 bits
    union { float f; unsigned u; } v; v.f = f;
    unsigned r = (v.u + 0x7FFFu + ((v.u >> 16) & 1u)) >> 16;
    return (short)r;
}
__device__ inline float bf2f(short s) {
    union { float f; unsigned u; } v;
    v.u = ((unsigned)(unsigned short)s) << 16;
    return v.f;
}

// ---------------------------------------------------------------------------
// k_wh: unchanged (passed).
// ---------------------------------------------------------------------------
__global__ __launch_bounds__(256) void k_wh(const float* __restrict__ h,
                                            const float* __restrict__ W,
                                            const float* __restrict__ a,
                                            const int* __restrict__ adj,
                                            short* __restrict__ WhHiT,
                                            short* __restrict__ WhLoT,
                                            float* __restrict__ f1,
                                            float* __restrict__ f2,
                                            u32* __restrict__ adjp) {
    __shared__ float Wa[2 * FF];
    __shared__ float hs[16 * 128];  // 8 KB
    int tid = threadIdx.x;
    int r0 = blockIdx.x * 16;

    {
        int fin = tid & 127;
        const float* av = (tid < 128) ? a : (a + FF);
        const float* wr = W + (size_t)fin * FF;
        float s = 0.f;
        for (int o = 0; o < FF; o += 4) {
            float4 wv = *(const float4*)(wr + o);
            float4 avv = *(const float4*)(av + o);
            s += wv.x * avv.x + wv.y * avv.y + wv.z * avv.z + wv.w * avv.w;
        }
        Wa[(tid < 128 ? 0 : FF) + fin] = s;
    }
    {
        const float4* src = (const float4*)(h + (size_t)r0 * FF);
        float4* dst = (float4*)hs;
        dst[tid] = src[tid];
        dst[256 + tid] = src[256 + tid];
    }
    // de-serialized adj pack: 512 blocks * 256 thr = 131072 = 2048 rows * 64 words
    {
        int g = blockIdx.x * 256 + tid;
        int row = g >> 6, wd = g & 63;
        const int4* ar = (const int4*)(adj + (size_t)row * NN + wd * 32);
        u32 word = 0;
#pragma unroll
        for (int q = 0; q < 8; ++q) {
            int4 v = ar[q];
            word |= (u32)(v.x > 0) << (q * 4);
            word |= (u32)(v.y > 0) << (q * 4 + 1);
            word |= (u32)(v.z > 0) << (q * 4 + 2);
            word |= (u32)(v.w > 0) << (q * 4 + 3);
        }
        adjp[row * 64 + wd] = word;
    }
    __syncthreads();

    {
        int w = tid >> 6, lane = tid & 63;
        float wa1_0 = Wa[lane], wa1_1 = Wa[lane + 64];
        float wa2_0 = Wa[FF + lane], wa2_1 = Wa[FF + lane + 64];
        for (int rr = 0; rr < 4; ++rr) {
            int rloc = w * 4 + rr;
            int row = r0 + rloc;
            float x0 = hs[rloc * FF + lane], x1 = hs[rloc * FF + lane + 64];
            float s1 = x0 * wa1_0 + x1 * wa1_1;
            float s2 = x0 * wa2_0 + x1 * wa2_1;
#pragma unroll
            for (int m = 32; m >= 1; m >>= 1) {
                s1 += __shfl_xor(s1, m, 64);
                s2 += __shfl_xor(s2, m, 64);
            }
            if (lane == 0) { f1[row] = s1; f2[row] = s2; }
        }
    }

    int f4 = (tid & 31) * 4;
    int rg = tid >> 5;  // 0..7
    float acc[2][4];
#pragma unroll
    for (int rr = 0; rr < 2; ++rr)
#pragma unroll
        for (int cc = 0; cc < 4; ++cc) acc[rr][cc] = 0.f;

    for (int k0 = 0; k0 < FF; k0 += 4) {
        float4 wv[4];
#pragma unroll
        for (int kk = 0; kk < 4; ++kk)
            wv[kk] = *(const float4*)(W + (size_t)(k0 + kk) * FF + f4);
        float4 hv[2];
#pragma unroll
        for (int rr = 0; rr < 2; ++rr)
            hv[rr] = *(const float4*)(hs + (rg * 2 + rr) * FF + k0);
#pragma unroll
        for (int rr = 0; rr < 2; ++rr) {
            float hk[4] = {hv[rr].x, hv[rr].y, hv[rr].z, hv[rr].w};
#pragma unroll
            for (int kk = 0; kk < 4; ++kk) {
                acc[rr][0] += hk[kk] * wv[kk].x;
                acc[rr][1] += hk[kk] * wv[kk].y;
                acc[rr][2] += hk[kk] * wv[kk].z;
                acc[rr][3] += hk[kk] * wv[kk].w;
            }
        }
    }
    int rloc = r0 + rg * 2;
    int b = rloc >> 11;
    int j = rloc & (NN - 1);  // even
#pragma unroll
    for (int cc = 0; cc < 4; ++cc) {
        float v0 = acc[0][cc], v1 = acc[1][cc];
        short h0 = f2bf(v0), h1 = f2bf(v1);
        short l0 = f2bf(v0 - bf2f(h0)), l1 = f2bf(v1 - bf2f(h1));
        size_t off = (size_t)(b * FF + f4 + cc) * NP + j;
        *(short2*)(WhHiT + off) = make_short2(h0, h1);
        *(short2*)(WhLoT + off) = make_short2(l0, l1);
    }
}

// ---------------------------------------------------------------------------
// k_attn v8 "wave-autonomous": rounds 0-2 proved the lockstep 8-wave barrier
// loop is convoy-bound (~3750 cy/period vs ~1000 cy of pipe work; 3 structural
// nulls at 50us). v8 removes the structure: each wave owns 8 complete j-steps
// (all 4 ni, both mi => 8 private f32x4 accs), computes its A-fragments
// IN REGISTERS (lane l: row=l&15, k=(l>>4)*8+e -- layout proven by v5-v7's
// working LDS read pattern), loads B-fragments straight from L2-resident
// WhT (lane-quads cover 64B contiguous; consecutive steps touch the other
// half of each 128B line). ZERO barriers in the main loop; every exp
// computed exactly once. Epilogue: 8 partial images merged via XOR-swizzled
// col-major LDS (conflict-free), row-sum combine, normalized store.
// ---------------------------------------------------------------------------
#define EV(f2v, f1v, wv, bi) ({ float _t = (f1v) + (f2v); float _x = fmaxf(_t, ALPHA * _t); \
    __expf(_x - SHIFT_C) * (float)(((wv) >> (bi)) & 1u); })

__global__ __launch_bounds__(512, 4) void k_attn(const short* __restrict__ WhHiT,
                                                 const short* __restrict__ WhLoT,
                                                 const u32* __restrict__ adjp,
                                                 const float* __restrict__ f1,
                                                 const float* __restrict__ f2,
                                                 float* __restrict__ out) {
    __shared__ __align__(16) char lds[66688];  // 8 x 8KB images + row_ps 1KB + row_inv 128B
    float* row_ps = (float*)(lds + 65536);     // [8][32]
    float* row_inv = (float*)(lds + 66560);    // [32]

    int tid = threadIdx.x;
    int w = tid >> 6, lane = tid & 63;
    int blk = blockIdx.x;
    int b = blk >> 7;
    int tile = (blk >> 1) & 63;
    int half = blk & 1;
    int i0 = tile * 32;

    int r_c = lane & 15, kg = lane >> 4;

    const float* f2b = f2 + b * NN;
    float f10 = f1[b * NN + i0 + r_c];        // mi=0 row
    float f11 = f1[b * NN + i0 + 16 + r_c];   // mi=1 row
    const u32* ap0 = adjp + (size_t)(i0 + r_c) * 64;
    const u32* ap1 = adjp + (size_t)(i0 + 16 + r_c) * 64;

    // B-fragment row pointers (hi); lo at constant element delta
    const ptrdiff_t dLo = (ptrdiff_t)BB * FF * NP;
    int s0 = w * 8;  // this wave's first step (contiguous 8 steps)
    const short* pB0 = WhHiT + (size_t)(b * FF + half * 64 + 0 * 16 + r_c) * NP + s0 * 32 + kg * 8;
    const short* pB1 = WhHiT + (size_t)(b * FF + half * 64 + 1 * 16 + r_c) * NP + s0 * 32 + kg * 8;
    const short* pB2 = WhHiT + (size_t)(b * FF + half * 64 + 2 * 16 + r_c) * NP + s0 * 32 + kg * 8;
    const short* pB3 = WhHiT + (size_t)(b * FF + half * 64 + 3 * 16 + r_c) * NP + s0 * 32 + kg * 8;

    f32x4 acc0_0 = {0,0,0,0}, acc0_1 = {0,0,0,0};
    f32x4 acc1_0 = {0,0,0,0}, acc1_1 = {0,0,0,0};
    f32x4 acc2_0 = {0,0,0,0}, acc2_1 = {0,0,0,0};
    f32x4 acc3_0 = {0,0,0,0}, acc3_1 = {0,0,0,0};
    float sp0 = 0.f, sp1 = 0.f;

    // prologue: scalars for step s0
    float4 q0 = *(const float4*)(f2b + s0 * 32 + kg * 8);
    float4 q1 = *(const float4*)(f2b + s0 * 32 + kg * 8 + 4);
    u32 w0 = ap0[s0], w1 = ap1[s0];

#pragma unroll
    for (int s8 = 0; s8 < 8; ++s8) {
        // B loads for this step (8 x 16B; consumed after ~350cy of e-compute)
        bf16x8 bh0 = *(const bf16x8*)(pB0); bf16x8 bl0 = *(const bf16x8*)(pB0 + dLo);
        bf16x8 bh1 = *(const bf16x8*)(pB1); bf16x8 bl1 = *(const bf16x8*)(pB1 + dLo);
        bf16x8 bh2 = *(const bf16x8*)(pB2); bf16x8 bl2 = *(const bf16x8*)(pB2 + dLo);
        bf16x8 bh3 = *(const bf16x8*)(pB3); bf16x8 bl3 = *(const bf16x8*)(pB3 + dLo);
        // prefetch next step's scalars (wrap harmless)
        int sn = (s0 + s8 + 1) & 63;
        float4 nq0 = *(const float4*)(f2b + sn * 32 + kg * 8);
        float4 nq1 = *(const float4*)(f2b + sn * 32 + kg * 8 + 4);
        u32 nw0 = ap0[sn], nw1 = ap1[sn];

        // in-register A fragments: lane holds rows r_c (mi=0), 16+r_c (mi=1),
        // k-elements j = s*32 + kg*8 + e  (bit kg*8+e of adjp word s)
        union { u32 u[4]; bf16x8 v; } A0, A1;
        int bb = kg * 8;
        {
            float pa, pb;
            pa = EV(q0.x, f10, w0, bb + 0); pb = EV(q0.y, f10, w0, bb + 1);
            sp0 += pa + pb;
            asm("v_cvt_pk_bf16_f32 %0, %1, %2" : "=v"(A0.u[0]) : "v"(pa), "v"(pb));
            pa = EV(q0.z, f10, w0, bb + 2); pb = EV(q0.w, f10, w0, bb + 3);
            sp0 += pa + pb;
            asm("v_cvt_pk_bf16_f32 %0, %1, %2" : "=v"(A0.u[1]) : "v"(pa), "v"(pb));
            pa = EV(q1.x, f10, w0, bb + 4); pb = EV(q1.y, f10, w0, bb + 5);
            sp0 += pa + pb;
            asm("v_cvt_pk_bf16_f32 %0, %1, %2" : "=v"(A0.u[2]) : "v"(pa), "v"(pb));
            pa = EV(q1.z, f10, w0, bb + 6); pb = EV(q1.w, f10, w0, bb + 7);
            sp0 += pa + pb;
            asm("v_cvt_pk_bf16_f32 %0, %1, %2" : "=v"(A0.u[3]) : "v"(pa), "v"(pb));

            pa = EV(q0.x, f11, w1, bb + 0); pb = EV(q0.y, f11, w1, bb + 1);
            sp1 += pa + pb;
            asm("v_cvt_pk_bf16_f32 %0, %1, %2" : "=v"(A1.u[0]) : "v"(pa), "v"(pb));
            pa = EV(q0.z, f11, w1, bb + 2); pb = EV(q0.w, f11, w1, bb + 3);
            sp1 += pa + pb;
            asm("v_cvt_pk_bf16_f32 %0, %1, %2" : "=v"(A1.u[1]) : "v"(pa), "v"(pb));
            pa = EV(q1.x, f11, w1, bb + 4); pb = EV(q1.y, f11, w1, bb + 5);
            sp1 += pa + pb;
            asm("v_cvt_pk_bf16_f32 %0, %1, %2" : "=v"(A1.u[2]) : "v"(pa), "v"(pb));
            pa = EV(q1.z, f11, w1, bb + 6); pb = EV(q1.w, f11, w1, bb + 7);
            sp1 += pa + pb;
            asm("v_cvt_pk_bf16_f32 %0, %1, %2" : "=v"(A1.u[3]) : "v"(pa), "v"(pb));
        }

        // 8 MFMA: out = A x (Bhi + Blo), both halves into the same acc
        acc0_0 = __builtin_amdgcn_mfma_f32_16x16x32_bf16(A0.v, bh0, acc0_0, 0, 0, 0);
        acc0_0 = __builtin_amdgcn_mfma_f32_16x16x32_bf16(A0.v, bl0, acc0_0, 0, 0, 0);
        acc0_1 = __builtin_amdgcn_mfma_f32_16x16x32_bf16(A1.v, bh0, acc0_1, 0, 0, 0);
        acc0_1 = __builtin_amdgcn_mfma_f32_16x16x32_bf16(A1.v, bl0, acc0_1, 0, 0, 0);
        acc1_0 = __builtin_amdgcn_mfma_f32_16x16x32_bf16(A0.v, bh1, acc1_0, 0, 0, 0);
        acc1_0 = __builtin_amdgcn_mfma_f32_16x16x32_bf16(A0.v, bl1, acc1_0, 0, 0, 0);
        acc1_1 = __builtin_amdgcn_mfma_f32_16x16x32_bf16(A1.v, bh1, acc1_1, 0, 0, 0);
        acc1_1 = __builtin_amdgcn_mfma_f32_16x16x32_bf16(A1.v, bl1, acc1_1, 0, 0, 0);
        acc2_0 = __builtin_amdgcn_mfma_f32_16x16x32_bf16(A0.v, bh2, acc2_0, 0, 0, 0);
        acc2_0 = __builtin_amdgcn_mfma_f32_16x16x32_bf16(A0.v, bl2, acc2_0, 0, 0, 0);
        acc2_1 = __builtin_amdgcn_mfma_f32_16x16x32_bf16(A1.v, bh2, acc2_1, 0, 0, 0);
        acc2_1 = __builtin_amdgcn_mfma_f32_16x16x32_bf16(A1.v, bl2, acc2_1, 0, 0, 0);
        acc3_0 = __builtin_amdgcn_mfma_f32_16x16x32_bf16(A0.v, bh3, acc3_0, 0, 0, 0);
        acc3_0 = __builtin_amdgcn_mfma_f32_16x16x32_bf16(A0.v, bl3, acc3_0, 0, 0, 0);
        acc3_1 = __builtin_amdgcn_mfma_f32_16x16x32_bf16(A1.v, bh3, acc3_1, 0, 0, 0);
        acc3_1 = __builtin_amdgcn_mfma_f32_16x16x32_bf16(A1.v, bl3, acc3_1, 0, 0, 0);

        // advance
        pB0 += 32; pB1 += 32; pB2 += 32; pB3 += 32;
        q0 = nq0; q1 = nq1; w0 = nw0; w1 = nw1;
    }

    // ---- epilogue ----
    // wave-local row-sum reduce: lanes {r, r+16, r+32, r+48} hold k-slices of row r
    sp0 += __shfl_xor(sp0, 16, 64); sp0 += __shfl_xor(sp0, 32, 64);
    sp1 += __shfl_xor(sp1, 16, 64); sp1 += __shfl_xor(sp1, 32, 64);
    if (lane < 16) {
        row_ps[w * 32 + lane] = sp0;
        row_ps[w * 32 + 16 + lane] = sp1;
    }
    // write this wave's partial image, col-major [col][row] f32, XOR-swizzled
    // 16B chunks (chunk = col*8 + mi*4 + kg, key = col&7) -> 2-way max on write
    {
        char* img = lds + w * 8192;
#define STACC(NI, MI, A) { int ch = (((NI)*16 + r_c) * 8 + (MI)*4 + kg) ^ (r_c & 7); \
                           *(f32x4*)(img + ch * 16) = (A); }
        STACC(0, 0, acc0_0) STACC(0, 1, acc0_1)
        STACC(1, 0, acc1_0) STACC(1, 1, acc1_1)
        STACC(2, 0, acc2_0) STACC(2, 1, acc2_1)
        STACC(3, 0, acc3_0) STACC(3, 1, acc3_1)
#undef STACC
    }
    __syncthreads();
    if (tid < 32) {
        float t = 0.f;
#pragma unroll
        for (int ww = 0; ww < 8; ++ww) t += row_ps[ww * 32 + tid];
        row_inv[tid] = 1.0f / t;
    }
    __syncthreads();

    // merge 8 images + normalize + store. wave w: cols w*8+(lane>>3), rows (lane&7)*4..+3
    {
        int colg = w * 8 + (lane >> 3);
        int rq = lane & 7;
        int ch = (colg * 8 + rq) ^ (colg & 7);
        f32x4 v = {0, 0, 0, 0};
#pragma unroll
        for (int im = 0; im < 8; ++im)
            v += *(const f32x4*)(lds + im * 8192 + ch * 16);
        f32x4 rinv = *(const f32x4*)((char*)row_inv + rq * 16);
        float* ob = out + ((size_t)b * NN + i0 + rq * 4) * FF + half * 64 + colg;
#pragma unroll
        for (int q = 0; q < 4; ++q)
            ob[(size_t)q * FF] = v[q] * rinv[q];
    }
}

// ---------------------------------------------------------------------------
extern "C" void kernel_launch(void* const* d_in, const int* in_sizes, int n_in,
                              void* d_out, int out_size, void* d_ws, size_t ws_size,
                              hipStream_t stream) {
    const float* h   = (const float*)d_in[0];
    const int*   adj = (const int*)d_in[1];
    const float* W   = (const float*)d_in[2];
    const float* a   = (const float*)d_in[3];
    float* out = (float*)d_out;

    short* WhHiT = (short*)d_ws;                          // 2.13 MB
    short* WhLoT = WhHiT + (size_t)BB * FF * NP;          // 2.13 MB
    float* f1 = (float*)(WhLoT + (size_t)BB * FF * NP);   // 32 KB
    float* f2 = f1 + (size_t)BB * NN;                     // 32 KB
    u32* adjp = (u32*)(f2 + (size_t)BB * NN);             // 512 KB (total ~4.83 MB, proven)

    k_wh<<<(BB * NN) / 16, 256, 0, stream>>>(h, W, a, adj, WhHiT, WhLoT, f1, f2, adjp);
    k_attn<<<512, 512, 0, stream>>>(WhHiT, WhLoT, adjp, f1, f2, out);
}